// Round 1
// baseline (580.349 us; speedup 1.0000x reference)
//
#include <hip/hip_runtime.h>

#define NSEQ  9216
#define CDIM  192
#define NSPLIT 2
#define KEYS_PER_SPLIT (NSEQ / NSPLIT)   // 4608
#define KTILE 64
#define KITERS (KEYS_PER_SPLIT / KTILE)  // 72

typedef _Float16 h8_t __attribute__((ext_vector_type(8)));
typedef _Float16 h4_t __attribute__((ext_vector_type(4)));
typedef float    f4_t __attribute__((ext_vector_type(4)));

// ---------------------------------------------------------------------------
// Kernel 1: QKV projection (fp32 math, f16 outputs)
//   QT[b][n][o] = sum_c Wq[o][c] x[b][c][n] + bq[o]   (c-contiguous rows)
//   KT[b][n][o] likewise; Vg[b][o][n] in original layout (n-contiguous)
// ---------------------------------------------------------------------------
__global__ __launch_bounds__(192) void proj_kernel(
    const float* __restrict__ x,
    const float* __restrict__ Wq, const float* __restrict__ bq,
    const float* __restrict__ Wk, const float* __restrict__ bk,
    const float* __restrict__ Wv, const float* __restrict__ bv,
    _Float16* __restrict__ QT, _Float16* __restrict__ KT, _Float16* __restrict__ Vg)
{
    __shared__ __align__(16) float Xs[CDIM][64];
    const int tid = threadIdx.x;
    const int b  = blockIdx.y;
    const int n0 = blockIdx.x * 64;

    // stage X tile [192 c][64 n], coalesced (lane = n)
    for (int i = tid; i < CDIM * 64; i += 192) {
        int n = i & 63, c = i >> 6;
        Xs[c][n] = x[(b * CDIM + c) * NSEQ + n0 + n];
    }
    __syncthreads();

    const int o = tid;                      // 192 threads = 192 output channels
    const float* Ws[3] = {Wq, Wk, Wv};
    const float* bs[3] = {bq, bk, bv};

    for (int mat = 0; mat < 3; mat++) {
        const float* W = Ws[mat] + o * CDIM;
        float bias = bs[mat][o];
        float acc[64];
        #pragma unroll
        for (int n = 0; n < 64; n++) acc[n] = 0.f;

        for (int c = 0; c < CDIM; c++) {
            float w = W[c];
            const f4_t* xr = (const f4_t*)&Xs[c][0];  // broadcast reads
            #pragma unroll
            for (int n4 = 0; n4 < 16; n4++) {
                f4_t xv = xr[n4];
                acc[n4*4+0] += w * xv[0];
                acc[n4*4+1] += w * xv[1];
                acc[n4*4+2] += w * xv[2];
                acc[n4*4+3] += w * xv[3];
            }
        }

        if (mat < 2) {
            _Float16* outp = (mat == 0) ? QT : KT;
            #pragma unroll 8
            for (int n = 0; n < 64; n++)
                outp[(b * NSEQ + n0 + n) * CDIM + o] = (_Float16)(acc[n] + bias);
        } else {
            _Float16* vp = Vg + (size_t)(b * CDIM + o) * NSEQ + n0;
            #pragma unroll
            for (int n8 = 0; n8 < 8; n8++) {
                h8_t h;
                #pragma unroll
                for (int j = 0; j < 8; j++) h[j] = (_Float16)(acc[n8*8 + j] + bias);
                *(h8_t*)(vp + n8 * 8) = h;
            }
        }
    }
}

// ---------------------------------------------------------------------------
// Kernel 2: flash attention, S^T trick.
//   Per wave: 16 queries. Block = 4 waves = 64 queries. Key-split = 2.
//   S^T[key,q] = K_tile * Q  -> C/D layout puts q = lane&15 (cheap softmax).
//   P -> LDS -> A-frag; O^T[q][c] += P * V.  Partials (O,m,l) to workspace.
// ---------------------------------------------------------------------------
__global__ __launch_bounds__(256, 2) void flash_kernel(
    const _Float16* __restrict__ QT, const _Float16* __restrict__ KTg,
    const _Float16* __restrict__ Vg,
    float* __restrict__ O_part, float* __restrict__ m_part, float* __restrict__ l_part)
{
    __shared__ __align__(16) _Float16 K_s[KTILE * 200];   // [key][c], stride 200 (pad)
    __shared__ __align__(16) _Float16 V_s[CDIM * 72];     // [c][n],  stride 72  (pad)
    __shared__ __align__(16) _Float16 P_s[4 * 16 * 72];   // per-wave [q][key], stride 72
    __shared__ __align__(16) float alpha_s[4][16];

    const int tid  = threadIdx.x;
    const int lane = tid & 63, wave = tid >> 6;
    const int L15  = lane & 15, quad = lane >> 4;
    const int qtile = blockIdx.x, split = blockIdx.y, b = blockIdx.z;
    const int q0 = qtile * 64 + wave * 16;

    // resident Q B-fragments: B[k=c][col=q], 16B contiguous reads from QT[q][c]
    h8_t qf[6];
    const _Float16* qbase = QT + ((size_t)b * NSEQ + q0 + L15) * CDIM + quad * 8;
    #pragma unroll
    for (int kw = 0; kw < 6; kw++) qf[kw] = *(const h8_t*)(qbase + kw * 32);

    f4_t acc[12];
    #pragma unroll
    for (int i = 0; i < 12; i++) acc[i] = (f4_t){0.f, 0.f, 0.f, 0.f};
    float m_run = -__builtin_inff();
    float l_run = 0.f;

    const int key_base = split * KEYS_PER_SPLIT;
    const _Float16* ksrc = KTg + ((size_t)b * NSEQ + key_base) * CDIM;
    const _Float16* vsrc = Vg + (size_t)b * CDIM * NSEQ + key_base;

    for (int kt = 0; kt < KITERS; kt++) {
        __syncthreads();
        // stage K tile: 64 rows x 192 c = 1536 16B-chunks, globally contiguous
        {
            const h8_t* src = (const h8_t*)(ksrc + (size_t)kt * KTILE * CDIM);
            #pragma unroll
            for (int t = 0; t < 6; t++) {
                int i = tid + t * 256;
                int row = i / 24, col = i % 24;
                *(h8_t*)(K_s + row * 200 + col * 8) = src[i];
            }
            // stage V tile: 192 rows x 64 n = 1536 chunks
            #pragma unroll
            for (int t = 0; t < 6; t++) {
                int i = tid + t * 256;
                int c = i >> 3, seg = i & 7;
                *(h8_t*)(V_s + c * 72 + seg * 8) =
                    *(const h8_t*)(vsrc + (size_t)c * NSEQ + kt * KTILE + seg * 8);
            }
        }
        __syncthreads();

        // S^T = K_tile * Q : 4 key-subtiles x 6 k-steps
        f4_t st[4];
        #pragma unroll
        for (int s = 0; s < 4; s++) st[s] = (f4_t){0.f, 0.f, 0.f, 0.f};
        #pragma unroll
        for (int kw = 0; kw < 6; kw++) {
            #pragma unroll
            for (int s = 0; s < 4; s++) {
                h8_t a = *(const h8_t*)(K_s + (s * 16 + L15) * 200 + kw * 32 + quad * 8);
                st[s] = __builtin_amdgcn_mfma_f32_16x16x32_f16(a, qf[kw], st[s], 0, 0, 0);
            }
        }

        // online softmax: lane's q = L15; lane holds 16 keys (quad-strided)
        float mx = st[0][0];
        #pragma unroll
        for (int s = 0; s < 4; s++) {
            #pragma unroll
            for (int r = 0; r < 4; r++) mx = fmaxf(mx, st[s][r]);
        }
        mx = fmaxf(mx, __shfl_xor(mx, 16));
        mx = fmaxf(mx, __shfl_xor(mx, 32));
        float m_new = fmaxf(m_run, mx);

        float p[16];
        float psum = 0.f;
        #pragma unroll
        for (int s = 0; s < 4; s++) {
            #pragma unroll
            for (int r = 0; r < 4; r++) {
                float e = __expf(st[s][r] - m_new);
                p[s * 4 + r] = e;
                psum += e;
            }
        }

        bool resc = __any(m_new > m_run);
        if (resc) {
            float alpha = __expf(m_run - m_new);   // -inf -> 0 on first iter
            l_run = l_run * alpha + psum;
            if (lane < 16) alpha_s[wave][lane] = alpha;
            __asm__ volatile("" ::: "memory");
            f4_t a4 = *(const f4_t*)&alpha_s[wave][quad * 4];  // alpha for O rows quad*4+r
            #pragma unroll
            for (int ct = 0; ct < 12; ct++) {
                acc[ct][0] *= a4[0]; acc[ct][1] *= a4[1];
                acc[ct][2] *= a4[2]; acc[ct][3] *= a4[3];
            }
        } else {
            l_run += psum;
        }
        m_run = m_new;

        // P -> LDS as f16, layout [q][key] stride 72
        _Float16* prow = P_s + wave * 1152 + L15 * 72;
        #pragma unroll
        for (int s = 0; s < 4; s++) {
            h4_t h = {(_Float16)p[s*4+0], (_Float16)p[s*4+1],
                      (_Float16)p[s*4+2], (_Float16)p[s*4+3]};
            *(h4_t*)(prow + s * 16 + quad * 4) = h;
        }
        __asm__ volatile("" ::: "memory");

        // PV: O^T[q][c] += P[q][key] * V[c][key]
        h8_t pa0 = *(const h8_t*)(prow + quad * 8);
        h8_t pa1 = *(const h8_t*)(prow + 32 + quad * 8);
        #pragma unroll
        for (int ct = 0; ct < 12; ct++) {
            h8_t vb0 = *(const h8_t*)(V_s + (ct * 16 + L15) * 72 + quad * 8);
            h8_t vb1 = *(const h8_t*)(V_s + (ct * 16 + L15) * 72 + 32 + quad * 8);
            acc[ct] = __builtin_amdgcn_mfma_f32_16x16x32_f16(pa0, vb0, acc[ct], 0, 0, 0);
            acc[ct] = __builtin_amdgcn_mfma_f32_16x16x32_f16(pa1, vb1, acc[ct], 0, 0, 0);
        }
    }

    // epilogue: reduce l across quads, store unnormalized partials
    float l_tot = l_run;
    l_tot += __shfl_xor(l_tot, 16);
    l_tot += __shfl_xor(l_tot, 32);

    const size_t pbase = (size_t)(b * NSPLIT + split) * NSEQ + q0;
    if (lane < 16) {
        m_part[pbase + lane] = m_run;
        l_part[pbase + lane] = l_tot;
    }
    float* obase = O_part + pbase * CDIM;
    #pragma unroll
    for (int ct = 0; ct < 12; ct++) {
        #pragma unroll
        for (int r = 0; r < 4; r++)
            obase[(quad * 4 + r) * CDIM + ct * 16 + L15] = acc[ct][r];
    }
}

// ---------------------------------------------------------------------------
// Kernel 3: merge the 2 key-splits, normalize, transpose to out[b][c][n]
// ---------------------------------------------------------------------------
__global__ __launch_bounds__(256) void combine_kernel(
    const float* __restrict__ O_part, const float* __restrict__ m_part,
    const float* __restrict__ l_part, float* __restrict__ out)
{
    __shared__ float Cs[CDIM][65];
    const int tid = threadIdx.x;
    const int b  = blockIdx.y;
    const int n0 = blockIdx.x * 64;

    const int base1 = (b * NSPLIT + 0) * NSEQ;
    const int base2 = (b * NSPLIT + 1) * NSEQ;

    for (int i = tid; i < 64 * CDIM; i += 256) {
        int c = i % CDIM, nl = i / CDIM;
        int n = n0 + nl;
        float m1 = m_part[base1 + n], m2 = m_part[base2 + n];
        float l1 = l_part[base1 + n], l2 = l_part[base2 + n];
        float ms = fmaxf(m1, m2);
        float w1 = __expf(m1 - ms), w2 = __expf(m2 - ms);
        float denom = w1 * l1 + w2 * l2;
        float o1 = O_part[((size_t)base1 + n) * CDIM + c];
        float o2 = O_part[((size_t)base2 + n) * CDIM + c];
        Cs[c][nl] = (w1 * o1 + w2 * o2) / denom;
    }
    __syncthreads();
    for (int i = tid; i < CDIM * 64; i += 256) {
        int nl = i & 63, c = i >> 6;
        out[((size_t)b * CDIM + c) * NSEQ + n0 + nl] = Cs[c][nl];
    }
}

// ---------------------------------------------------------------------------
extern "C" void kernel_launch(void* const* d_in, const int* in_sizes, int n_in,
                              void* d_out, int out_size, void* d_ws, size_t ws_size,
                              hipStream_t stream)
{
    const float* x  = (const float*)d_in[0];
    const float* Wq = (const float*)d_in[1];
    const float* bq = (const float*)d_in[2];
    const float* Wk = (const float*)d_in[3];
    const float* bk = (const float*)d_in[4];
    const float* Wv = (const float*)d_in[5];
    const float* bv = (const float*)d_in[6];
    float* out = (float*)d_out;

    // workspace layout (all 16B aligned)
    char* ws = (char*)d_ws;
    _Float16* QT = (_Float16*)(ws);                 // 2*9216*192 f16 = 7,077,888 B
    _Float16* KT = (_Float16*)(ws + 7077888);
    _Float16* Vg = (_Float16*)(ws + 14155776);
    float* O_part = (float*)(ws + 21233664);        // 2*2*9216*192 f32 = 28,311,552 B
    float* m_part = (float*)(ws + 49545216);        // 2*2*9216 f32
    float* l_part = (float*)(ws + 49692672);        // total 49,840,128 B

    proj_kernel<<<dim3(144, 2), 192, 0, stream>>>(x, Wq, bq, Wk, bk, Wv, bv, QT, KT, Vg);
    flash_kernel<<<dim3(144, NSPLIT, 2), 256, 0, stream>>>(QT, KT, Vg, O_part, m_part, l_part);
    combine_kernel<<<dim3(144, 2), 256, 0, stream>>>(O_part, m_part, l_part, out);
}

// Round 2
// 302.926 us; speedup vs baseline: 1.9158x; 1.9158x over previous
//
#include <hip/hip_runtime.h>

#define NSEQ  9216
#define CDIM  192
#define KTILE 64

typedef _Float16 h8_t  __attribute__((ext_vector_type(8)));
typedef _Float16 h4_t  __attribute__((ext_vector_type(4)));
typedef float    f4_t  __attribute__((ext_vector_type(4)));
typedef float    f16v  __attribute__((ext_vector_type(16)));

// ---------------------------------------------------------------------------
// Kernel 0: convert Wq/Wk/Wv fp32 -> f16 contiguous Wh[3][192][192]
// ---------------------------------------------------------------------------
__global__ __launch_bounds__(256) void wconv_kernel(
    const float* __restrict__ Wq, const float* __restrict__ Wk,
    const float* __restrict__ Wv, _Float16* __restrict__ Wh)
{
    int i = blockIdx.x * 256 + threadIdx.x;     // f4 index, 3*9216 total
    if (i >= 3 * 9216) return;
    const float* src = (i < 9216) ? Wq : (i < 18432 ? Wk : Wv);
    int r = i % 9216;
    f4_t w = ((const f4_t*)src)[r];
    h4_t h = {(_Float16)w[0], (_Float16)w[1], (_Float16)w[2], (_Float16)w[3]};
    ((h4_t*)Wh)[i] = h;
}

// ---------------------------------------------------------------------------
// Kernel 1: QKV projection via 32x32x16 MFMA.
//   Per wave: 32 seq positions, all 192 out-channels, all 3 mats.
//   D[m=o][n=seq]: A = W[o][c] (f16, L2-hot), B = x^T frags (built from
//   coalesced fp32 loads). C/D: col=lane&31=seq, row=(reg&3)+8*(reg>>2)+4*hi.
// ---------------------------------------------------------------------------
__global__ __launch_bounds__(128) void proj_kernel(
    const float* __restrict__ x, const _Float16* __restrict__ Wh,
    const float* __restrict__ bq, const float* __restrict__ bk,
    const float* __restrict__ bv,
    _Float16* __restrict__ QT, _Float16* __restrict__ KT, _Float16* __restrict__ Vg)
{
    const int tid  = threadIdx.x;
    const int lane = tid & 63, wave = tid >> 6;
    const int L31  = lane & 31, hi = lane >> 5;
    const int idx  = blockIdx.x * 2 + wave;      // 0..575
    const int b    = idx / 288;
    const int n0   = (idx % 288) * 32;
    const int n    = n0 + L31;

    // B-fragments: B[col=seq=L31][k=c = t*16 + hi*8 + j]
    h8_t bf[12];
    #pragma unroll
    for (int t = 0; t < 12; t++) {
        h8_t h;
        #pragma unroll
        for (int j = 0; j < 8; j++)
            h[j] = (_Float16)x[(size_t)(b * CDIM + t * 16 + hi * 8 + j) * NSEQ + n];
        bf[t] = h;
    }

    const float* biases[3] = {bq, bk, bv};
    for (int mat = 0; mat < 3; mat++) {
        const _Float16* W = Wh + mat * CDIM * CDIM;
        f16v acc[6];
        #pragma unroll
        for (int s = 0; s < 6; s++)
            #pragma unroll
            for (int r = 0; r < 16; r++) acc[s][r] = 0.f;

        #pragma unroll
        for (int t = 0; t < 12; t++) {
            #pragma unroll
            for (int s = 0; s < 6; s++) {
                h8_t a = *(const h8_t*)(W + (s * 32 + L31) * CDIM + t * 16 + hi * 8);
                acc[s] = __builtin_amdgcn_mfma_f32_32x32x16_f16(a, bf[t], acc[s], 0, 0, 0);
            }
        }

        if (mat < 2) {
            _Float16* dst = ((mat == 0) ? QT : KT) + ((size_t)b * NSEQ + n) * CDIM;
            #pragma unroll
            for (int s = 0; s < 6; s++) {
                #pragma unroll
                for (int g = 0; g < 4; g++) {
                    f4_t bb = *(const f4_t*)&biases[mat][s * 32 + 8 * g + 4 * hi];
                    h4_t h = {(_Float16)(acc[s][4*g+0] + bb[0]),
                              (_Float16)(acc[s][4*g+1] + bb[1]),
                              (_Float16)(acc[s][4*g+2] + bb[2]),
                              (_Float16)(acc[s][4*g+3] + bb[3])};
                    *(h4_t*)(dst + s * 32 + 8 * g + 4 * hi) = h;
                }
            }
        } else {
            #pragma unroll
            for (int s = 0; s < 6; s++) {
                #pragma unroll
                for (int g = 0; g < 4; g++) {
                    f4_t bb = *(const f4_t*)&biases[2][s * 32 + 8 * g + 4 * hi];
                    #pragma unroll
                    for (int r = 0; r < 4; r++) {
                        int o = s * 32 + 8 * g + 4 * hi + r;
                        Vg[((size_t)b * CDIM + o) * NSEQ + n] =
                            (_Float16)(acc[s][4*g+r] + bb[r]);
                    }
                }
            }
        }
    }
}

// ---------------------------------------------------------------------------
// Kernel 2: flash attention, 32x32x16 MFMA, S^T trick.
//   Per wave: 32 queries (col = lane&31). Block = 4 waves = 128 queries.
//   All LDS strides: stride_dw == 4 (mod 32) -> uniform 8 lanes / 4-bank group.
// ---------------------------------------------------------------------------
template<int NSPLIT>
__global__ __launch_bounds__(256, 2) void flash_kernel(
    const _Float16* __restrict__ QT, const _Float16* __restrict__ KTg,
    const _Float16* __restrict__ Vg,
    _Float16* __restrict__ O_part, float* __restrict__ m_part, float* __restrict__ l_part)
{
    constexpr int KPS    = NSEQ / NSPLIT;
    constexpr int KITERS = KPS / KTILE;

    __shared__ __align__(16) _Float16 K_s[KTILE * 200];   // [key][c], 100 dw stride
    __shared__ __align__(16) _Float16 V_s[CDIM * 72];     // [c][key], 36 dw stride
    __shared__ __align__(16) _Float16 P_s[4 * 32 * 72];   // per-wave [q][key]
    __shared__ float alpha_s[4][32];

    const int tid  = threadIdx.x;
    const int lane = tid & 63, wave = tid >> 6;
    const int L31  = lane & 31, hi = lane >> 5;
    const int qtile = blockIdx.x, split = blockIdx.y, b = blockIdx.z;
    const int q0 = qtile * 128 + wave * 32;

    // resident Q B-fragments: B[col=q=L31][k=c]
    h8_t qf[12];
    const _Float16* qbase = QT + ((size_t)b * NSEQ + q0 + L31) * CDIM + hi * 8;
    #pragma unroll
    for (int t = 0; t < 12; t++) qf[t] = *(const h8_t*)(qbase + t * 16);

    f16v acc[6];
    #pragma unroll
    for (int s = 0; s < 6; s++)
        #pragma unroll
        for (int r = 0; r < 16; r++) acc[s][r] = 0.f;
    float m_run = -__builtin_inff();
    float l_run = 0.f;

    const _Float16* ksrc = KTg + ((size_t)b * NSEQ + split * KPS) * CDIM;
    const _Float16* vsrc = Vg + (size_t)b * CDIM * NSEQ + split * KPS;

    for (int kt = 0; kt < KITERS; kt++) {
        __syncthreads();
        {   // stage K tile: 64 keys x 192 ch
            const h8_t* src = (const h8_t*)(ksrc + (size_t)kt * KTILE * CDIM);
            #pragma unroll
            for (int t = 0; t < 6; t++) {
                int i = tid + t * 256;
                int row = i / 24, col = i % 24;
                *(h8_t*)(K_s + row * 200 + col * 8) = src[i];
            }
            // stage V tile: 192 ch x 64 keys
            #pragma unroll
            for (int t = 0; t < 6; t++) {
                int i = tid + t * 256;
                int c = i >> 3, seg = i & 7;
                *(h8_t*)(V_s + c * 72 + seg * 8) =
                    *(const h8_t*)(vsrc + (size_t)c * NSEQ + kt * KTILE + seg * 8);
            }
        }
        __syncthreads();

        // S^T = K_tile * Q : 2 key-subtiles x 12 k-steps
        f16v st[2];
        #pragma unroll
        for (int s = 0; s < 2; s++)
            #pragma unroll
            for (int r = 0; r < 16; r++) st[s][r] = 0.f;
        #pragma unroll
        for (int t = 0; t < 12; t++) {
            #pragma unroll
            for (int s = 0; s < 2; s++) {
                h8_t a = *(const h8_t*)(K_s + (s * 32 + L31) * 200 + t * 16 + hi * 8);
                st[s] = __builtin_amdgcn_mfma_f32_32x32x16_f16(a, qf[t], st[s], 0, 0, 0);
            }
        }

        // online softmax: lane's query = L31; lane holds 32 keys, partner(^32) other 32
        float mx = st[0][0];
        #pragma unroll
        for (int s = 0; s < 2; s++)
            #pragma unroll
            for (int r = 0; r < 16; r++) mx = fmaxf(mx, st[s][r]);
        mx = fmaxf(mx, __shfl_xor(mx, 32));
        float m_new = fmaxf(m_run, mx);

        float p[32];
        float psum = 0.f;
        #pragma unroll
        for (int s = 0; s < 2; s++)
            #pragma unroll
            for (int r = 0; r < 16; r++) {
                float e = __expf(st[s][r] - m_new);
                p[s * 16 + r] = e;
                psum += e;
            }

        if (__any(m_new > m_run)) {
            float alpha = __expf(m_run - m_new);    // -inf -> 0 on first iter
            l_run = l_run * alpha + psum;
            if (lane < 32) alpha_s[wave][lane] = alpha;
            __asm__ volatile("" ::: "memory");
            f4_t a4[4];
            #pragma unroll
            for (int g = 0; g < 4; g++)
                a4[g] = *(const f4_t*)&alpha_s[wave][8 * g + 4 * hi];
            #pragma unroll
            for (int cs = 0; cs < 6; cs++)
                #pragma unroll
                for (int r = 0; r < 16; r++) acc[cs][r] *= a4[r >> 2][r & 3];
        } else {
            l_run += psum;
        }
        m_run = m_new;

        // P -> LDS, [q][key] (key = s*32 + 8g + 4hi + r)
        _Float16* prow = P_s + wave * 32 * 72 + L31 * 72;
        #pragma unroll
        for (int s = 0; s < 2; s++)
            #pragma unroll
            for (int g = 0; g < 4; g++) {
                h4_t h = {(_Float16)p[s*16+4*g+0], (_Float16)p[s*16+4*g+1],
                          (_Float16)p[s*16+4*g+2], (_Float16)p[s*16+4*g+3]};
                *(h4_t*)(prow + s * 32 + 8 * g + 4 * hi) = h;
            }
        __asm__ volatile("" ::: "memory");

        // PV: O^T[q][c] += P[q][key] * V[c][key]
        #pragma unroll
        for (int ks = 0; ks < 4; ks++) {
            h8_t pa = *(const h8_t*)(prow + ks * 16 + hi * 8);
            #pragma unroll
            for (int cs = 0; cs < 6; cs++) {
                h8_t vb = *(const h8_t*)(V_s + (cs * 32 + L31) * 72 + ks * 16 + hi * 8);
                acc[cs] = __builtin_amdgcn_mfma_f32_32x32x16_f16(pa, vb, acc[cs], 0, 0, 0);
            }
        }
    }

    // epilogue: unnormalized partials
    float l_tot = l_run + __shfl_xor(l_run, 32);
    const size_t pbase = (size_t)(b * NSPLIT + split) * NSEQ + q0;
    if (lane < 32) {
        m_part[pbase + lane] = m_run;
        l_part[pbase + lane] = l_tot;
    }
    _Float16* obase = O_part + pbase * CDIM;
    #pragma unroll
    for (int cs = 0; cs < 6; cs++)
        #pragma unroll
        for (int r = 0; r < 16; r++) {
            int q = (r & 3) + 8 * (r >> 2) + 4 * hi;
            obase[(size_t)q * CDIM + cs * 32 + L31] = (_Float16)acc[cs][r];
        }
}

// ---------------------------------------------------------------------------
// Kernel 3: merge NS splits, normalize, transpose to out[b][c][n]
// ---------------------------------------------------------------------------
template<int NS>
__global__ __launch_bounds__(256) void combine_kernel(
    const _Float16* __restrict__ O_part, const float* __restrict__ m_part,
    const float* __restrict__ l_part, float* __restrict__ out)
{
    __shared__ float Cs[CDIM][65];
    __shared__ float winv[NS][64];
    const int tid = threadIdx.x;
    const int b  = blockIdx.y;
    const int n0 = blockIdx.x * 64;

    if (tid < 64) {
        int n = n0 + tid;
        float mm[NS], ll[NS], ms = -__builtin_inff();
        #pragma unroll
        for (int s = 0; s < NS; s++) {
            mm[s] = m_part[(b * NS + s) * NSEQ + n];
            ll[s] = l_part[(b * NS + s) * NSEQ + n];
            ms = fmaxf(ms, mm[s]);
        }
        float denom = 0.f;
        #pragma unroll
        for (int s = 0; s < NS; s++) {
            float w = __expf(mm[s] - ms);
            mm[s] = w;
            denom += w * ll[s];
        }
        #pragma unroll
        for (int s = 0; s < NS; s++) winv[s][tid] = mm[s] / denom;
    }
    __syncthreads();

    for (int i = tid; i < 64 * 96; i += 256) {
        int nl = i / 96, cp = i % 96;
        float v0 = 0.f, v1 = 0.f;
        #pragma unroll
        for (int s = 0; s < NS; s++) {
            const _Float16* op =
                O_part + ((size_t)(b * NS + s) * NSEQ + n0 + nl) * CDIM + cp * 2;
            float w = winv[s][nl];
            v0 += w * (float)op[0];
            v1 += w * (float)op[1];
        }
        Cs[cp * 2][nl] = v0;
        Cs[cp * 2 + 1][nl] = v1;
    }
    __syncthreads();
    for (int i = tid; i < CDIM * 64; i += 256) {
        int nl = i & 63, c = i >> 6;
        out[((size_t)b * CDIM + c) * NSEQ + n0 + nl] = Cs[c][nl];
    }
}

// ---------------------------------------------------------------------------
extern "C" void kernel_launch(void* const* d_in, const int* in_sizes, int n_in,
                              void* d_out, int out_size, void* d_ws, size_t ws_size,
                              hipStream_t stream)
{
    const float* x  = (const float*)d_in[0];
    const float* Wq = (const float*)d_in[1];
    const float* bq = (const float*)d_in[2];
    const float* Wk = (const float*)d_in[3];
    const float* bk = (const float*)d_in[4];
    const float* Wv = (const float*)d_in[5];
    const float* bv = (const float*)d_in[6];
    float* out = (float*)d_out;

    // workspace layout
    char* ws = (char*)d_ws;
    _Float16* QT = (_Float16*)(ws);                    // 7,077,888 B
    _Float16* KT = (_Float16*)(ws + 7077888);
    _Float16* Vg = (_Float16*)(ws + 14155776);
    char* tail = ws + 21233664;
    _Float16* Wh = (_Float16*)tail;                    // 221,184 B, aliases O_part
    _Float16* O_part = (_Float16*)tail;                // NS * 7,077,888 B (f16)

    wconv_kernel<<<108, 256, 0, stream>>>(Wq, Wk, Wv, Wh);
    proj_kernel<<<288, 128, 0, stream>>>(x, Wh, bq, bk, bv, QT, KT, Vg);

    const size_t need8 = 21233664ull + 8 * 7077888ull + 2 * 589824ull;  // 79,036,416
    const size_t need4 = 21233664ull + 4 * 7077888ull + 2 * 294912ull;  // 50,135,040
    if (ws_size >= need8) {
        float* m_part = (float*)(tail + 8 * 7077888ull);
        float* l_part = (float*)(tail + 8 * 7077888ull + 589824ull);
        flash_kernel<8><<<dim3(72, 8, 2), 256, 0, stream>>>(QT, KT, Vg, O_part, m_part, l_part);
        combine_kernel<8><<<dim3(144, 2), 256, 0, stream>>>(O_part, m_part, l_part, out);
    } else if (ws_size >= need4) {
        float* m_part = (float*)(tail + 4 * 7077888ull);
        float* l_part = (float*)(tail + 4 * 7077888ull + 294912ull);
        flash_kernel<4><<<dim3(72, 4, 2), 256, 0, stream>>>(QT, KT, Vg, O_part, m_part, l_part);
        combine_kernel<4><<<dim3(144, 2), 256, 0, stream>>>(O_part, m_part, l_part, out);
    } else {
        float* m_part = (float*)(tail + 2 * 7077888ull);
        float* l_part = (float*)(tail + 2 * 7077888ull + 147456ull);
        flash_kernel<2><<<dim3(72, 2, 2), 256, 0, stream>>>(QT, KT, Vg, O_part, m_part, l_part);
        combine_kernel<2><<<dim3(144, 2), 256, 0, stream>>>(O_part, m_part, l_part, out);
    }
}